// Round 9
// baseline (185.089 us; speedup 1.0000x reference)
//
#include <hip/hip_runtime.h>

#define D    2048
#define NB   32
#define BD   64
#define HD   128
#define WSZ  (NB * HD * BD)   // 262144 elems per weight matrix
#define NCH  64               // row-chunks per block-column (grid = NB*NCH = 2048)

typedef __attribute__((ext_vector_type(8))) short short8;
typedef __attribute__((ext_vector_type(4))) float floatx4;

static __device__ __forceinline__ unsigned short f2bf(float f) {
  union { float f; unsigned u; } v; v.f = f;
  return (unsigned short)((v.u + 0x7FFFu + ((v.u >> 16) & 1u)) >> 16);
}
static __device__ __forceinline__ float bf2f(unsigned short h) {
  union { unsigned u; float f; } v; v.u = ((unsigned)h) << 16;
  return v.f;
}
static __device__ __forceinline__ unsigned fbits(float f) {
  union { float f; unsigned u; } v; v.f = f; return v.u;
}
// TRUNCATION bf16x2 pack in ONE v_perm_b32:
// dst = {hi16(b), hi16(a)}  (byte sel: 0-3 from 2nd arg, 4-7 from 1st arg)
static __device__ __forceinline__ unsigned pkt(float a, float b) {
  return __builtin_amdgcn_perm(fbits(b), fbits(a), 0x07060302u);
}
static __device__ __forceinline__ float fast_exp2(float x) {
  float r; asm("v_exp_f32 %0, %1" : "=v"(r) : "v"(x)); return r;
}
static __device__ __forceinline__ float fast_rcp(float x) {
  float r; asm("v_rcp_f32 %0, %1" : "=v"(r) : "v"(x)); return r;
}
// sigmoid-form GELU (validated r1-r8)
static __device__ __forceinline__ float gelu_f(float x) {
  float x2 = x * x;
  float w  = __builtin_fmaf(x2, -0.102943695f, -2.3022083f);
  float e  = fast_exp2(x * w);
  return x * fast_rcp(1.0f + e);
}

// padded LDS index for the permute kernels (stride 72 keeps 8B alignment)
static __device__ __forceinline__ int pidx(int s) { return s + ((s >> 6) << 3); }

// ---------------------------------------------------------------------------
// Block-major MLP layer, round-9:
//  - zero-DS H (k-permuted W2) + 32KB LDS weights (r7, validated)
//  - ALL intermediate bf16 packing via 1-inst v_perm_b32 truncation (pkt);
//    final layer-1 store keeps RNE f2bf.  (r8 audit: __float22bfloat162_rn
//    is ~11 VALU inst/pair -> was ~40% of all VALU)
//  - LDS reads via per-matrix base pointer + compile-time immediate offsets
//  - grid 2048, 2 tiles/wave, both tiles loaded before weight staging
// ---------------------------------------------------------------------------
template<bool F32IN>
__global__ __launch_bounds__(512, 4) void mlp_layer(
    const float* __restrict__ xf,      // used when F32IN
    unsigned short* yio,               // bf16 input (when !F32IN) AND output
    const unsigned short* __restrict__ Wt1,  // [n][128][64] bf16, swizzled
    const unsigned short* __restrict__ Wt2,  // [n][64][128] bf16, slot-permuted+swizzled
    const float* __restrict__ b1,
    const float* __restrict__ b2) {
  __shared__ unsigned short Wlds[16384];     // 32KB: [0..8191]=W1t, [8192..]=W2t
  const int n     = blockIdx.x >> 6;
  const int chunk = blockIdx.x & (NCH - 1);
  const int t = threadIdx.x, wv = t >> 6, l = t & 63;
  const int lr = l & 15, q = l >> 4;
  const int sw = (lr & 7) << 3;
  const int rbase = chunk * 256 + wv * 32 + lr;   // 2 tiles: +0, +16

  // ---- issue BOTH activation tile loads first (cover = staging+barrier) ----
  float4 uf[2][4];
  short8 xp[2][2];
  if constexpr (F32IN) {
#pragma unroll
    for (int p = 0; p < 2; ++p) {
      const float* xr = xf + (size_t)(rbase + p * 16) * D + n * BD + q * 8;
      uf[p][0] = *(const float4*)(xr);      uf[p][1] = *(const float4*)(xr + 4);
      uf[p][2] = *(const float4*)(xr + 32); uf[p][3] = *(const float4*)(xr + 36);
    }
  } else {
#pragma unroll
    for (int p = 0; p < 2; ++p) {
      const unsigned short* yr = yio + (size_t)(rbase + p * 16) * D + n * BD + q * 8;
      xp[p][0] = *(const short8*)(yr); xp[p][1] = *(const short8*)(yr + 32);
    }
  }

  // ---- stage both weight matrices into LDS (linear copy of prepped image) ----
  {
    const unsigned short* s1 = Wt1 + n * 8192;
    const unsigned short* s2 = Wt2 + n * 8192;
#pragma unroll
    for (int i = 0; i < 2; ++i) {
      const int e = (i * 512 + t) * 8;
      *(short8*)&Wlds[e]        = *(const short8*)&s1[e];
      *(short8*)&Wlds[8192 + e] = *(const short8*)&s2[e];
    }
  }

  // ---- biases -> accumulator-init fragments (loaded once per WG) ----
  floatx4 bias1v[8], bias2v[4];
#pragma unroll
  for (int hf = 0; hf < 2; ++hf)
#pragma unroll
    for (int ot = 0; ot < 4; ++ot) {
      const float4 bb = *(const float4*)&b1[n * HD + hf * 64 + ot * 16 + q * 4];
      floatx4 v; v[0] = bb.x; v[1] = bb.y; v[2] = bb.z; v[3] = bb.w;
      bias1v[hf * 4 + ot] = v;
    }
#pragma unroll
  for (int ot = 0; ot < 4; ++ot) {
    const float4 bb = *(const float4*)&b2[n * BD + ot * 16 + q * 4];
    floatx4 v; v[0] = bb.x; v[1] = bb.y; v[2] = bb.z; v[3] = bb.w;
    bias2v[ot] = v;
  }

  // per-matrix LDS base pointers; all fragment reads become base + imm offset
  const unsigned short* w1p0 = &Wlds[lr * 64 + ((q * 8) ^ sw)];
  const unsigned short* w1p1 = &Wlds[lr * 64 + ((32 + q * 8) ^ sw)];
  const unsigned short* w2p0 = &Wlds[8192 + lr * 128 + ((q * 8) ^ sw)];
  const unsigned short* w2p1 = &Wlds[8192 + lr * 128 + (((32 + q * 8)) ^ sw)];

  __syncthreads();   // weights staged

#pragma unroll
  for (int i = 0; i < 2; ++i) {
    short8 xb0, xb1;
    if constexpr (F32IN) {
      union { unsigned u[4]; short8 s; } c0, c1;
      c0.u[0] = pkt(uf[i][0].x, uf[i][0].y);
      c0.u[1] = pkt(uf[i][0].z, uf[i][0].w);
      c0.u[2] = pkt(uf[i][1].x, uf[i][1].y);
      c0.u[3] = pkt(uf[i][1].z, uf[i][1].w);
      c1.u[0] = pkt(uf[i][2].x, uf[i][2].y);
      c1.u[1] = pkt(uf[i][2].z, uf[i][2].w);
      c1.u[2] = pkt(uf[i][3].x, uf[i][3].y);
      c1.u[3] = pkt(uf[i][3].z, uf[i][3].w);
      xb0 = c0.s; xb1 = c1.s;
    } else {
      xb0 = xp[i][0]; xb1 = xp[i][1];
    }

    floatx4 acc2[4] = {bias2v[0], bias2v[1], bias2v[2], bias2v[3]};
#pragma unroll
    for (int hf = 0; hf < 2; ++hf) {
      floatx4 acc1[4] = {bias1v[hf * 4 + 0], bias1v[hf * 4 + 1],
                         bias1v[hf * 4 + 2], bias1v[hf * 4 + 3]};
      // GEMM1: A-frags from LDS, compile-time offsets
#pragma unroll
      for (int ot = 0; ot < 4; ++ot) {
        const int off = (hf * 64 + ot * 16) * 64;
        short8 a0 = *(const short8*)&w1p0[off];
        short8 a1 = *(const short8*)&w1p1[off];
        acc1[ot] = __builtin_amdgcn_mfma_f32_16x16x32_bf16(a0, xb0, acc1[ot], 0, 0, 0);
        acc1[ot] = __builtin_amdgcn_mfma_f32_16x16x32_bf16(a1, xb1, acc1[ot], 0, 0, 0);
      }
      // gelu + 1-inst trunc pack -> GEMM2 B-frags (zero-DS H)
      union { unsigned u[4]; short8 s; } hb0, hb1;
      hb0.u[0] = pkt(gelu_f(acc1[0][0]), gelu_f(acc1[0][1]));
      hb0.u[1] = pkt(gelu_f(acc1[0][2]), gelu_f(acc1[0][3]));
      hb0.u[2] = pkt(gelu_f(acc1[1][0]), gelu_f(acc1[1][1]));
      hb0.u[3] = pkt(gelu_f(acc1[1][2]), gelu_f(acc1[1][3]));
      hb1.u[0] = pkt(gelu_f(acc1[2][0]), gelu_f(acc1[2][1]));
      hb1.u[1] = pkt(gelu_f(acc1[2][2]), gelu_f(acc1[2][3]));
      hb1.u[2] = pkt(gelu_f(acc1[3][0]), gelu_f(acc1[3][1]));
      hb1.u[3] = pkt(gelu_f(acc1[3][2]), gelu_f(acc1[3][3]));
      // GEMM2: A-frags from LDS (slot-permuted), compile-time offsets
#pragma unroll
      for (int ot = 0; ot < 4; ++ot) {
        const int off = ot * 16 * 128 + hf * 64;
        short8 w0 = *(const short8*)&w2p0[off];
        short8 w1 = *(const short8*)&w2p1[off];
        acc2[ot] = __builtin_amdgcn_mfma_f32_16x16x32_bf16(w0, hb0.s, acc2[ot], 0, 0, 0);
        acc2[ot] = __builtin_amdgcn_mfma_f32_16x16x32_bf16(w1, hb1.s, acc2[ot], 0, 0, 0);
      }
    }

    // ---- store: trunc pack for intermediate (layer0), RNE for final (layer1)
    unsigned short* yo = yio + (size_t)(rbase + i * 16) * D + n * BD;
#pragma unroll
    for (int ot = 0; ot < 4; ++ot) {
      if constexpr (F32IN) {
        uint2 ov;
        ov.x = pkt(acc2[ot][0], acc2[ot][1]);
        ov.y = pkt(acc2[ot][2], acc2[ot][3]);
        *(uint2*)&yo[ot * 16 + q * 4] = ov;
      } else {
        ushort4 ov;
        ov.x = f2bf(acc2[ot][0]);
        ov.y = f2bf(acc2[ot][1]);
        ov.z = f2bf(acc2[ot][2]);
        ov.w = f2bf(acc2[ot][3]);
        *(ushort4*)&yo[ot * 16 + q * 4] = ov;
      }
    }
  }
}

// ---------------------------------------------------------------------------
// In-place 64x64 transpose of each 2-row (4096-elem) group of Y, via LDS.
// ---------------------------------------------------------------------------
__global__ __launch_bounds__(256) void permute_k(unsigned short* Y) {
  __shared__ unsigned short L[4096 + 64 * 8];
  const int t = threadIdx.x;
  for (int gi = 0; gi < 8; ++gi) {
    unsigned short* Yg = Y + ((size_t)blockIdx.x * 8 + gi) * 4096;
    short8 v0 = *(const short8*)&Yg[t * 16];
    short8 v1 = *(const short8*)&Yg[t * 16 + 8];
    const int pb = pidx(t * 16);
    *(short4*)&L[pb +  0] = *((short4*)&v0);
    *(short4*)&L[pb +  4] = *((short4*)&v0 + 1);
    *(short4*)&L[pb +  8] = *((short4*)&v1);
    *(short4*)&L[pb + 12] = *((short4*)&v1 + 1);
    __syncthreads();
    unsigned short g[16];
    const int j = t >> 2, i0 = (t & 3) * 16;
#pragma unroll
    for (int k = 0; k < 16; ++k) g[k] = L[pidx((i0 + k) * 64 + j)];
    short8 o0, o1;
#pragma unroll
    for (int k = 0; k < 8; ++k) { o0[k] = (short)g[k]; o1[k] = (short)g[8 + k]; }
    __syncthreads();
    *(short8*)&Yg[t * 16]     = o0;
    *(short8*)&Yg[t * 16 + 8] = o1;
  }
}

// ---------------------------------------------------------------------------
// Final: un-permute (same 64x64 group transpose) + bf16 -> f32 store to out.
// ---------------------------------------------------------------------------
__global__ __launch_bounds__(256) void unpermute_k(const unsigned short* __restrict__ Y,
                                                   float* __restrict__ out) {
  __shared__ unsigned short L[4096 + 64 * 8];
  const int t = threadIdx.x;
  for (int gi = 0; gi < 8; ++gi) {
    const size_t gbase = ((size_t)blockIdx.x * 8 + gi) * 4096;
    const unsigned short* Yg = Y + gbase;
    short8 v0 = *(const short8*)&Yg[t * 16];
    short8 v1 = *(const short8*)&Yg[t * 16 + 8];
    const int pb = pidx(t * 16);
    *(short4*)&L[pb +  0] = *((short4*)&v0);
    *(short4*)&L[pb +  4] = *((short4*)&v0 + 1);
    *(short4*)&L[pb +  8] = *((short4*)&v1);
    *(short4*)&L[pb + 12] = *((short4*)&v1 + 1);
    __syncthreads();
    const int o0f = t * 16;
    const int a = o0f >> 11, c0 = o0f & 2047;
    const int s0 = (c0 & 63) * 64 + (a << 5) + (c0 >> 6);
    float f[16];
#pragma unroll
    for (int k = 0; k < 16; ++k) f[k] = bf2f(L[pidx(s0 + k * 64)]);
    __syncthreads();
    float* op = out + gbase + o0f;
#pragma unroll
    for (int k = 0; k < 4; ++k) {
      float4 fv; fv.x = f[4 * k]; fv.y = f[4 * k + 1]; fv.z = f[4 * k + 2]; fv.w = f[4 * k + 3];
      *(float4*)(op + 4 * k) = fv;
    }
  }
}

// W [n][R][C] f32 -> Wt [n][C][R] bf16, transposed + XOR-swizzled.
// W2 (odd segs) additionally gets the k-axis SLOT PERMUTATION so GEMM1's
// C-layout accumulator is directly a GEMM2 B-fragment:
//   slot q*8+j  holds  k-feature (j>>2)*16 + q*4 + (j&3)   (per 32-wide step)
__global__ void prep_w_all(const float* __restrict__ W1_0, const float* __restrict__ W2_0,
                           const float* __restrict__ W1_1, const float* __restrict__ W2_1,
                           unsigned short* __restrict__ dst) {
  const int seg = blockIdx.x >> 10;
  const int id  = ((blockIdx.x & 1023) << 8) | threadIdx.x;
  const float* W; int R;
  if      (seg == 0) { W = W1_0; R = BD; }
  else if (seg == 1) { W = W2_0; R = HD; }
  else if (seg == 2) { W = W1_1; R = BD; }
  else               { W = W2_1; R = HD; }
  const int C   = (R == BD) ? HD : BD;
  const int n   = id >> 13;
  const int rem = id & 8191;
  const int c   = rem / R;          // dst row (out-feature)
  const int r   = rem - c * R;      // dst col (k index)
  const unsigned short val = f2bf(W[(n * R + r) * C + c]);
  if (seg & 1) {
    // W2: k-feature r -> slot (bijective), then bank swizzle
    const int hf  = r >> 6, st = (r >> 5) & 1, blk = (r >> 4) & 1;
    const int qq  = (r & 15) >> 2, e = r & 3;
    const int slot = hf * 64 + st * 32 + qq * 8 + blk * 4 + e;
    dst[seg * WSZ + n * 8192 + c * HD + (slot ^ ((c & 7) << 3))] = val;
  } else {
    dst[seg * WSZ + n * 8192 + c * BD + (r ^ ((c & 7) << 3))] = val;
  }
}

extern "C" void kernel_launch(void* const* d_in, const int* in_sizes, int n_in,
                              void* d_out, int out_size, void* d_ws, size_t ws_size,
                              hipStream_t stream) {
  const float* x    = (const float*)d_in[0];
  const float* W1_0 = (const float*)d_in[1];
  const float* b1_0 = (const float*)d_in[2];
  const float* W2_0 = (const float*)d_in[3];
  const float* b2_0 = (const float*)d_in[4];
  const float* W1_1 = (const float*)d_in[5];
  const float* b1_1 = (const float*)d_in[6];
  const float* W2_1 = (const float*)d_in[7];
  const float* b2_1 = (const float*)d_in[8];
  float* out = (float*)d_out;

  // ws layout: [Wt: 4 x 512KB = 2MB][Y: 16384*2048 bf16 = 64MB]
  unsigned short* Wt = (unsigned short*)d_ws;
  unsigned short* Y  = Wt + 4 * WSZ;

  prep_w_all<<<4096, 256, 0, stream>>>(W1_0, W2_0, W1_1, W2_1, Wt);
  mlp_layer<true ><<<NB * NCH, 512, 0, stream>>>(x, Y, Wt, Wt + WSZ, b1_0, b2_0);
  permute_k<<<1024, 256, 0, stream>>>(Y);
  mlp_layer<false><<<NB * NCH, 512, 0, stream>>>(nullptr, Y, Wt + 2 * WSZ, Wt + 3 * WSZ, b1_1, b2_1);
  unpermute_k<<<1024, 256, 0, stream>>>(Y, out);
}

// Round 10
// 177.408 us; speedup vs baseline: 1.0433x; 1.0433x over previous
//
#include <hip/hip_runtime.h>

#define D    2048
#define NB   32
#define BD   64
#define HD   128
#define WSZ  (NB * HD * BD)   // 262144 elems per weight matrix
#define NCH  64               // row-chunks per block-column (grid = NB*NCH = 2048)

typedef __attribute__((ext_vector_type(8))) short short8;
typedef __attribute__((ext_vector_type(4))) float floatx4;

static __device__ __forceinline__ unsigned short f2bf(float f) {
  union { float f; unsigned u; } v; v.f = f;
  return (unsigned short)((v.u + 0x7FFFu + ((v.u >> 16) & 1u)) >> 16);
}
static __device__ __forceinline__ float bf2f(unsigned short h) {
  union { unsigned u; float f; } v; v.u = ((unsigned)h) << 16;
  return v.f;
}
static __device__ __forceinline__ unsigned fbits(float f) {
  union { float f; unsigned u; } v; v.f = f; return v.u;
}
// TRUNCATION bf16x2 pack in ONE v_perm_b32 (validated r9, absmax 384 < 586)
static __device__ __forceinline__ unsigned pkt(float a, float b) {
  return __builtin_amdgcn_perm(fbits(b), fbits(a), 0x07060302u);
}
static __device__ __forceinline__ float fast_exp2(float x) {
  float r; asm("v_exp_f32 %0, %1" : "=v"(r) : "v"(x)); return r;
}
static __device__ __forceinline__ float fast_rcp(float x) {
  float r; asm("v_rcp_f32 %0, %1" : "=v"(r) : "v"(x)); return r;
}
// sigmoid-form GELU (validated r1-r9)
static __device__ __forceinline__ float gelu_f(float x) {
  float x2 = x * x;
  float w  = __builtin_fmaf(x2, -0.102943695f, -2.3022083f);
  float e  = fast_exp2(x * w);
  return x * fast_rcp(1.0f + e);
}

// padded LDS index for the permute kernels (stride 72 keeps 8B alignment)
static __device__ __forceinline__ int pidx(int s) { return s + ((s >> 6) << 3); }

// ---------------------------------------------------------------------------
// Round-10: r9 compute structure (zero-DS H, k-permuted W2, pkt packs) with
// FORCED load-issue ordering. r9 audit: VGPR_Count=60 while the written
// prefetch set needs >=128 -> regalloc SANK the activation prefetches to
// their uses; each tile then eats exposed L2/HBM latency serially (the ~70%
// unaccounted stall). Fix: issue staging + bias + BOTH x-tile loads, then a
// compiler memory fence (loads can't sink past it), then LDS writes +
// barrier -> all load latency is absorbed ONCE per WG, compute runs clean.
// Biases live in LDS (frees 48 persistent VGPRs so the fix fits in 128).
// ---------------------------------------------------------------------------
template<bool F32IN>
__global__ __launch_bounds__(512, 4) void mlp_layer(
    const float* __restrict__ xf,      // used when F32IN
    unsigned short* yio,               // bf16 input (when !F32IN) AND output
    const unsigned short* __restrict__ Wt1,  // [n][128][64] bf16, swizzled
    const unsigned short* __restrict__ Wt2,  // [n][64][128] bf16, slot-permuted+swizzled
    const float* __restrict__ b1,
    const float* __restrict__ b2) {
  __shared__ unsigned short Wlds[16384];     // 32KB: [0..8191]=W1t, [8192..]=W2t
  __shared__ float Blds[192];                // b1[0..127], b2[128..191]
  const int n     = blockIdx.x >> 6;
  const int chunk = blockIdx.x & (NCH - 1);
  const int t = threadIdx.x, l = t & 63, wv = t >> 6;
  const int lr = l & 15, q = l >> 4;
  const int sw = (lr & 7) << 3;
  const int rbase = chunk * 256 + wv * 32 + lr;   // 2 tiles: +0, +16

  // ---- (1) issue weight-staging loads (FIFO-first: drain before x) ----
  const unsigned short* s1 = Wt1 + n * 8192;
  const unsigned short* s2 = Wt2 + n * 8192;
  short8 sv[4];
  sv[0] = *(const short8*)&s1[t * 8];
  sv[1] = *(const short8*)&s1[(512 + t) * 8];
  sv[2] = *(const short8*)&s2[t * 8];
  sv[3] = *(const short8*)&s2[(512 + t) * 8];

  // ---- (2) issue bias loads ----
  float bv = 0.f;
  if (t < 128)      bv = b1[n * HD + t];
  else if (t < 192) bv = b2[n * BD + (t - 128)];

  // ---- (3) issue BOTH activation tile loads ----
  float4 uf[2][4];
  short8 xp[2][2];
  if constexpr (F32IN) {
#pragma unroll
    for (int p = 0; p < 2; ++p) {
      const float* xr = xf + (size_t)(rbase + p * 16) * D + n * BD + q * 8;
      uf[p][0] = *(const float4*)(xr);      uf[p][1] = *(const float4*)(xr + 4);
      uf[p][2] = *(const float4*)(xr + 32); uf[p][3] = *(const float4*)(xr + 36);
    }
  } else {
#pragma unroll
    for (int p = 0; p < 2; ++p) {
      const unsigned short* yr = yio + (size_t)(rbase + p * 16) * D + n * BD + q * 8;
      xp[p][0] = *(const short8*)(yr); xp[p][1] = *(const short8*)(yr + 32);
    }
  }

  // ---- (4) compiler memory fence: nothing above may sink below ----
  asm volatile("" ::: "memory");

  // ---- (5) LDS writes (wait staging loads only; x stays in flight) ----
  *(short8*)&Wlds[t * 8]              = sv[0];
  *(short8*)&Wlds[(512 + t) * 8]      = sv[1];
  *(short8*)&Wlds[8192 + t * 8]       = sv[2];
  *(short8*)&Wlds[8192 + (512 + t) * 8] = sv[3];
  if (t < 192) Blds[t] = bv;

  __syncthreads();   // weights+biases staged; all load latency absorbed here

  // per-matrix LDS base pointers; fragment reads = base + imm offset
  const unsigned short* w1p0 = &Wlds[lr * 64 + ((q * 8) ^ sw)];
  const unsigned short* w1p1 = &Wlds[lr * 64 + ((32 + q * 8) ^ sw)];
  const unsigned short* w2p0 = &Wlds[8192 + lr * 128 + ((q * 8) ^ sw)];
  const unsigned short* w2p1 = &Wlds[8192 + lr * 128 + ((32 + q * 8) ^ sw)];

#pragma unroll
  for (int i = 0; i < 2; ++i) {
    short8 xb0, xb1;
    if constexpr (F32IN) {
      union { unsigned u[4]; short8 s; } c0, c1;
      c0.u[0] = pkt(uf[i][0].x, uf[i][0].y);
      c0.u[1] = pkt(uf[i][0].z, uf[i][0].w);
      c0.u[2] = pkt(uf[i][1].x, uf[i][1].y);
      c0.u[3] = pkt(uf[i][1].z, uf[i][1].w);
      c1.u[0] = pkt(uf[i][2].x, uf[i][2].y);
      c1.u[1] = pkt(uf[i][2].z, uf[i][2].w);
      c1.u[2] = pkt(uf[i][3].x, uf[i][3].y);
      c1.u[3] = pkt(uf[i][3].z, uf[i][3].w);
      xb0 = c0.s; xb1 = c1.s;
    } else {
      xb0 = xp[i][0]; xb1 = xp[i][1];
    }

    // acc2 init = b2 fragment from LDS
    floatx4 acc2[4];
#pragma unroll
    for (int ot = 0; ot < 4; ++ot) {
      const float4 bb = *(const float4*)&Blds[128 + ot * 16 + q * 4];
      floatx4 v; v[0] = bb.x; v[1] = bb.y; v[2] = bb.z; v[3] = bb.w;
      acc2[ot] = v;
    }
#pragma unroll
    for (int hf = 0; hf < 2; ++hf) {
      // acc1 init = b1 fragment from LDS
      floatx4 acc1[4];
#pragma unroll
      for (int ot = 0; ot < 4; ++ot) {
        const float4 bb = *(const float4*)&Blds[hf * 64 + ot * 16 + q * 4];
        floatx4 v; v[0] = bb.x; v[1] = bb.y; v[2] = bb.z; v[3] = bb.w;
        acc1[ot] = v;
      }
      // GEMM1: A-frags from LDS, compile-time offsets
#pragma unroll
      for (int ot = 0; ot < 4; ++ot) {
        const int off = (hf * 64 + ot * 16) * 64;
        short8 a0 = *(const short8*)&w1p0[off];
        short8 a1 = *(const short8*)&w1p1[off];
        acc1[ot] = __builtin_amdgcn_mfma_f32_16x16x32_bf16(a0, xb0, acc1[ot], 0, 0, 0);
        acc1[ot] = __builtin_amdgcn_mfma_f32_16x16x32_bf16(a1, xb1, acc1[ot], 0, 0, 0);
      }
      // gelu + 1-inst trunc pack -> GEMM2 B-frags (zero-DS H)
      union { unsigned u[4]; short8 s; } hb0, hb1;
      hb0.u[0] = pkt(gelu_f(acc1[0][0]), gelu_f(acc1[0][1]));
      hb0.u[1] = pkt(gelu_f(acc1[0][2]), gelu_f(acc1[0][3]));
      hb0.u[2] = pkt(gelu_f(acc1[1][0]), gelu_f(acc1[1][1]));
      hb0.u[3] = pkt(gelu_f(acc1[1][2]), gelu_f(acc1[1][3]));
      hb1.u[0] = pkt(gelu_f(acc1[2][0]), gelu_f(acc1[2][1]));
      hb1.u[1] = pkt(gelu_f(acc1[2][2]), gelu_f(acc1[2][3]));
      hb1.u[2] = pkt(gelu_f(acc1[3][0]), gelu_f(acc1[3][1]));
      hb1.u[3] = pkt(gelu_f(acc1[3][2]), gelu_f(acc1[3][3]));
      // GEMM2: A-frags from LDS (slot-permuted), compile-time offsets
#pragma unroll
      for (int ot = 0; ot < 4; ++ot) {
        const int off = ot * 16 * 128 + hf * 64;
        short8 w0 = *(const short8*)&w2p0[off];
        short8 w1 = *(const short8*)&w2p1[off];
        acc2[ot] = __builtin_amdgcn_mfma_f32_16x16x32_bf16(w0, hb0.s, acc2[ot], 0, 0, 0);
        acc2[ot] = __builtin_amdgcn_mfma_f32_16x16x32_bf16(w1, hb1.s, acc2[ot], 0, 0, 0);
      }
    }

    // ---- store: trunc pack for intermediate (layer0), RNE for final (layer1)
    unsigned short* yo = yio + (size_t)(rbase + i * 16) * D + n * BD;
#pragma unroll
    for (int ot = 0; ot < 4; ++ot) {
      if constexpr (F32IN) {
        uint2 ov;
        ov.x = pkt(acc2[ot][0], acc2[ot][1]);
        ov.y = pkt(acc2[ot][2], acc2[ot][3]);
        *(uint2*)&yo[ot * 16 + q * 4] = ov;
      } else {
        ushort4 ov;
        ov.x = f2bf(acc2[ot][0]);
        ov.y = f2bf(acc2[ot][1]);
        ov.z = f2bf(acc2[ot][2]);
        ov.w = f2bf(acc2[ot][3]);
        *(ushort4*)&yo[ot * 16 + q * 4] = ov;
      }
    }
  }
}

// ---------------------------------------------------------------------------
// In-place 64x64 transpose of each 2-row (4096-elem) group of Y, via LDS.
// ---------------------------------------------------------------------------
__global__ __launch_bounds__(256) void permute_k(unsigned short* Y) {
  __shared__ unsigned short L[4096 + 64 * 8];
  const int t = threadIdx.x;
  for (int gi = 0; gi < 8; ++gi) {
    unsigned short* Yg = Y + ((size_t)blockIdx.x * 8 + gi) * 4096;
    short8 v0 = *(const short8*)&Yg[t * 16];
    short8 v1 = *(const short8*)&Yg[t * 16 + 8];
    const int pb = pidx(t * 16);
    *(short4*)&L[pb +  0] = *((short4*)&v0);
    *(short4*)&L[pb +  4] = *((short4*)&v0 + 1);
    *(short4*)&L[pb +  8] = *((short4*)&v1);
    *(short4*)&L[pb + 12] = *((short4*)&v1 + 1);
    __syncthreads();
    unsigned short g[16];
    const int j = t >> 2, i0 = (t & 3) * 16;
#pragma unroll
    for (int k = 0; k < 16; ++k) g[k] = L[pidx((i0 + k) * 64 + j)];
    short8 o0, o1;
#pragma unroll
    for (int k = 0; k < 8; ++k) { o0[k] = (short)g[k]; o1[k] = (short)g[8 + k]; }
    __syncthreads();
    *(short8*)&Yg[t * 16]     = o0;
    *(short8*)&Yg[t * 16 + 8] = o1;
  }
}

// ---------------------------------------------------------------------------
// Final: un-permute (same 64x64 group transpose) + bf16 -> f32 store to out.
// ---------------------------------------------------------------------------
__global__ __launch_bounds__(256) void unpermute_k(const unsigned short* __restrict__ Y,
                                                   float* __restrict__ out) {
  __shared__ unsigned short L[4096 + 64 * 8];
  const int t = threadIdx.x;
  for (int gi = 0; gi < 8; ++gi) {
    const size_t gbase = ((size_t)blockIdx.x * 8 + gi) * 4096;
    const unsigned short* Yg = Y + gbase;
    short8 v0 = *(const short8*)&Yg[t * 16];
    short8 v1 = *(const short8*)&Yg[t * 16 + 8];
    const int pb = pidx(t * 16);
    *(short4*)&L[pb +  0] = *((short4*)&v0);
    *(short4*)&L[pb +  4] = *((short4*)&v0 + 1);
    *(short4*)&L[pb +  8] = *((short4*)&v1);
    *(short4*)&L[pb + 12] = *((short4*)&v1 + 1);
    __syncthreads();
    const int o0f = t * 16;
    const int a = o0f >> 11, c0 = o0f & 2047;
    const int s0 = (c0 & 63) * 64 + (a << 5) + (c0 >> 6);
    float f[16];
#pragma unroll
    for (int k = 0; k < 16; ++k) f[k] = bf2f(L[pidx(s0 + k * 64)]);
    __syncthreads();
    float* op = out + gbase + o0f;
#pragma unroll
    for (int k = 0; k < 4; ++k) {
      float4 fv; fv.x = f[4 * k]; fv.y = f[4 * k + 1]; fv.z = f[4 * k + 2]; fv.w = f[4 * k + 3];
      *(float4*)(op + 4 * k) = fv;
    }
  }
}

// W [n][R][C] f32 -> Wt [n][C][R] bf16, transposed + XOR-swizzled.
// W2 (odd segs) additionally gets the k-axis SLOT PERMUTATION so GEMM1's
// C-layout accumulator is directly a GEMM2 B-fragment:
//   slot q*8+j  holds  k-feature (j>>2)*16 + q*4 + (j&3)   (per 32-wide step)
__global__ void prep_w_all(const float* __restrict__ W1_0, const float* __restrict__ W2_0,
                           const float* __restrict__ W1_1, const float* __restrict__ W2_1,
                           unsigned short* __restrict__ dst) {
  const int seg = blockIdx.x >> 10;
  const int id  = ((blockIdx.x & 1023) << 8) | threadIdx.x;
  const float* W; int R;
  if      (seg == 0) { W = W1_0; R = BD; }
  else if (seg == 1) { W = W2_0; R = HD; }
  else if (seg == 2) { W = W1_1; R = BD; }
  else               { W = W2_1; R = HD; }
  const int C   = (R == BD) ? HD : BD;
  const int n   = id >> 13;
  const int rem = id & 8191;
  const int c   = rem / R;          // dst row (out-feature)
  const int r   = rem - c * R;      // dst col (k index)
  const unsigned short val = f2bf(W[(n * R + r) * C + c]);
  if (seg & 1) {
    // W2: k-feature r -> slot (bijective), then bank swizzle
    const int hf  = r >> 6, st = (r >> 5) & 1, blk = (r >> 4) & 1;
    const int qq  = (r & 15) >> 2, e = r & 3;
    const int slot = hf * 64 + st * 32 + qq * 8 + blk * 4 + e;
    dst[seg * WSZ + n * 8192 + c * HD + (slot ^ ((c & 7) << 3))] = val;
  } else {
    dst[seg * WSZ + n * 8192 + c * BD + (r ^ ((c & 7) << 3))] = val;
  }
}

extern "C" void kernel_launch(void* const* d_in, const int* in_sizes, int n_in,
                              void* d_out, int out_size, void* d_ws, size_t ws_size,
                              hipStream_t stream) {
  const float* x    = (const float*)d_in[0];
  const float* W1_0 = (const float*)d_in[1];
  const float* b1_0 = (const float*)d_in[2];
  const float* W2_0 = (const float*)d_in[3];
  const float* b2_0 = (const float*)d_in[4];
  const float* W1_1 = (const float*)d_in[5];
  const float* b1_1 = (const float*)d_in[6];
  const float* W2_1 = (const float*)d_in[7];
  const float* b2_1 = (const float*)d_in[8];
  float* out = (float*)d_out;

  // ws layout: [Wt: 4 x 512KB = 2MB][Y: 16384*2048 bf16 = 64MB]
  unsigned short* Wt = (unsigned short*)d_ws;
  unsigned short* Y  = Wt + 4 * WSZ;

  prep_w_all<<<4096, 256, 0, stream>>>(W1_0, W2_0, W1_1, W2_1, Wt);
  mlp_layer<true ><<<NB * NCH, 512, 0, stream>>>(x, Y, Wt, Wt + WSZ, b1_0, b2_0);
  permute_k<<<1024, 256, 0, stream>>>(Y);
  mlp_layer<false><<<NB * NCH, 512, 0, stream>>>(nullptr, Y, Wt + 2 * WSZ, Wt + 3 * WSZ, b1_1, b2_1);
  unpermute_k<<<1024, 256, 0, stream>>>(Y, out);
}